// Round 3
// baseline (250.622 us; speedup 1.0000x reference)
//
#include <hip/hip_runtime.h>

#define BB   256
#define NIMG 49
#define NGPS 32
#define DIM  256
#define MPAD 64

typedef __attribute__((ext_vector_type(8))) __bf16 bf16x8;
typedef __attribute__((ext_vector_type(4))) float  f32x4;
typedef __attribute__((ext_vector_type(4))) unsigned short u16x4;

__device__ inline unsigned short f2bf(float f) {
  unsigned int u = __float_as_uint(f);
  u += 0x7fff + ((u >> 16) & 1);   // round-to-nearest-even
  return (unsigned short)(u >> 16);
}

// DPP cross-lane reduce helpers (VALU pipe, no DS traffic).
// 0xB1 quad_perm xor1, 0x4E quad_perm xor2, 0x141 row_half_mirror, 0x140 row_mirror
template<int CTRL>
__device__ inline float dppmax(float v) {
  float o = __int_as_float(__builtin_amdgcn_update_dpp(0, __float_as_int(v), CTRL, 0xF, 0xF, true));
  return fmaxf(v, o);
}
template<int CTRL>
__device__ inline float dppadd(float v) {
  float o = __int_as_float(__builtin_amdgcn_update_dpp(0, __float_as_int(v), CTRL, 0xF, 0xF, true));
  return v + o;
}
__device__ inline float max16(float v) {   // max across the 16 lanes of a DPP row
  v = dppmax<0xB1>(v); v = dppmax<0x4E>(v); v = dppmax<0x141>(v); v = dppmax<0x140>(v);
  return v;
}
__device__ inline float sum16(float v) {   // sum across the 16 lanes of a DPP row
  v = dppadd<0xB1>(v); v = dppadd<0x4E>(v); v = dppadd<0x141>(v); v = dppadd<0x140>(v);
  return v;
}

// ---------------- kernel 1: L2-normalize + cast to bf16 (img padded to 64 rows/b) ----
__global__ __launch_bounds__(256) void norm_kernel(
    const float* __restrict__ img, const float* __restrict__ gps,
    unsigned short* __restrict__ imgN, unsigned short* __restrict__ gpsN)
{
  int w    = (blockIdx.x * 256 + threadIdx.x) >> 6;  // one wave per row
  int lane = threadIdx.x & 63;
  const float* src;
  unsigned short* dst;
  if (w < BB * MPAD) {
    int b = w >> 6, n = w & 63;
    dst = imgN + (size_t)w * DIM;
    if (n >= NIMG) {                                  // zero padding rows
      u16x4 z = {0, 0, 0, 0};
      *reinterpret_cast<u16x4*>(dst + lane * 4) = z;
      return;
    }
    src = img + ((size_t)b * NIMG + n) * DIM;
  } else {
    int t = w - BB * MPAD;
    dst = gpsN + (size_t)t * DIM;
    src = gps + (size_t)t * DIM;
  }
  f32x4 x = *reinterpret_cast<const f32x4*>(src + lane * 4);
  float ss = x[0]*x[0] + x[1]*x[1] + x[2]*x[2] + x[3]*x[3];
  #pragma unroll
  for (int d = 1; d < 64; d <<= 1) ss += __shfl_xor(ss, d);
  float inv = 1.0f / fmaxf(sqrtf(ss), 1e-12f);
  u16x4 o;
  o[0] = f2bf(x[0]*inv); o[1] = f2bf(x[1]*inv);
  o[2] = f2bf(x[2]*inv); o[3] = f2bf(x[3]*inv);
  *reinterpret_cast<u16x4*>(dst + lane * 4) = o;
}

// ---------------- kernel 2: all-pairs 64x32 MFMA GEMM + fused max/mean reductions ----
// grid: 2048 blocks = 256 b * 8 g-chunks; 4 waves/block.
// A (img[b], 64x256 bf16 = 32KB) staged once in LDS, XOR-swizzled.
// Each wave owns 8 g's, processed 2 at a time (A fragment reuse x4 per ds_read).
__global__ __launch_bounds__(256, 3) void pair_kernel(
    const unsigned short* __restrict__ imgN, const unsigned short* __restrict__ gpsN,
    float* __restrict__ i2g, float* __restrict__ g2i)
{
  int tid  = threadIdx.x;
  int wv   = tid >> 6;
  int lane = tid & 63;
  int c    = lane & 15, grp = lane >> 4;
  int b    = blockIdx.x >> 3, gc = blockIdx.x & 7;

  __shared__ unsigned short As[MPAD * DIM];   // 32 KB

  // ---- stage A: lane = row, each wave writes 8 of 32 16B-slots per row ----
  {
    const unsigned short* src = imgN + ((size_t)(b * MPAD + lane)) * DIM;
    unsigned int rb = lane * 512;             // row byte base (512 B/row)
    unsigned int sw = (lane & 7) << 4;        // XOR swizzle for this row
    #pragma unroll
    for (int i = 0; i < 8; ++i) {
      int s = wv * 8 + i;                     // 16B slot index 0..31
      bf16x8 v = *reinterpret_cast<const bf16x8*>(src + s * 8);
      *reinterpret_cast<bf16x8*>(reinterpret_cast<char*>(As) + ((rb + s * 16) ^ sw)) = v;
    }
  }
  __syncthreads();

  const char* Ab = reinterpret_cast<const char*>(As);
  unsigned int swr = (c & 7) << 4;            // read-side swizzle (r&7 == c&7)
  unsigned int rbase0 = (c) * 512;            // mt stride added as mt*16*512

  #pragma unroll 1
  for (int st = 0; st < 4; ++st) {
    int g0 = gc * 32 + wv * 8 + st * 2;
    int g1 = g0 + 1;
    const unsigned short* p0 = gpsN + ((size_t)g0 * NGPS + c) * DIM + grp * 8;
    const unsigned short* p1 = gpsN + ((size_t)g1 * NGPS + c) * DIM + grp * 8;

    f32x4 acc[2][4][2];
    #pragma unroll
    for (int gg = 0; gg < 2; ++gg)
      #pragma unroll
      for (int mt = 0; mt < 4; ++mt) {
        acc[gg][mt][0] = (f32x4){0.f, 0.f, 0.f, 0.f};
        acc[gg][mt][1] = (f32x4){0.f, 0.f, 0.f, 0.f};
      }

    #pragma unroll
    for (int kc = 0; kc < 8; ++kc) {
      unsigned int off = ((unsigned)(grp * 16 + kc * 64)) ^ swr;
      bf16x8 a0 = *reinterpret_cast<const bf16x8*>(Ab + rbase0 +  0 * 8192 + off);
      bf16x8 a1 = *reinterpret_cast<const bf16x8*>(Ab + rbase0 +  1 * 8192 + off);
      bf16x8 a2 = *reinterpret_cast<const bf16x8*>(Ab + rbase0 +  2 * 8192 + off);
      bf16x8 a3 = *reinterpret_cast<const bf16x8*>(Ab + rbase0 +  3 * 8192 + off);
      bf16x8 b00 = *reinterpret_cast<const bf16x8*>(p0 + kc * 32);
      bf16x8 b01 = *reinterpret_cast<const bf16x8*>(p0 + 16 * DIM + kc * 32);
      bf16x8 b10 = *reinterpret_cast<const bf16x8*>(p1 + kc * 32);
      bf16x8 b11 = *reinterpret_cast<const bf16x8*>(p1 + 16 * DIM + kc * 32);
      acc[0][0][0] = __builtin_amdgcn_mfma_f32_16x16x32_bf16(a0, b00, acc[0][0][0], 0, 0, 0);
      acc[0][1][0] = __builtin_amdgcn_mfma_f32_16x16x32_bf16(a1, b00, acc[0][1][0], 0, 0, 0);
      acc[0][2][0] = __builtin_amdgcn_mfma_f32_16x16x32_bf16(a2, b00, acc[0][2][0], 0, 0, 0);
      acc[0][3][0] = __builtin_amdgcn_mfma_f32_16x16x32_bf16(a3, b00, acc[0][3][0], 0, 0, 0);
      acc[0][0][1] = __builtin_amdgcn_mfma_f32_16x16x32_bf16(a0, b01, acc[0][0][1], 0, 0, 0);
      acc[0][1][1] = __builtin_amdgcn_mfma_f32_16x16x32_bf16(a1, b01, acc[0][1][1], 0, 0, 0);
      acc[0][2][1] = __builtin_amdgcn_mfma_f32_16x16x32_bf16(a2, b01, acc[0][2][1], 0, 0, 0);
      acc[0][3][1] = __builtin_amdgcn_mfma_f32_16x16x32_bf16(a3, b01, acc[0][3][1], 0, 0, 0);
      acc[1][0][0] = __builtin_amdgcn_mfma_f32_16x16x32_bf16(a0, b10, acc[1][0][0], 0, 0, 0);
      acc[1][1][0] = __builtin_amdgcn_mfma_f32_16x16x32_bf16(a1, b10, acc[1][1][0], 0, 0, 0);
      acc[1][2][0] = __builtin_amdgcn_mfma_f32_16x16x32_bf16(a2, b10, acc[1][2][0], 0, 0, 0);
      acc[1][3][0] = __builtin_amdgcn_mfma_f32_16x16x32_bf16(a3, b10, acc[1][3][0], 0, 0, 0);
      acc[1][0][1] = __builtin_amdgcn_mfma_f32_16x16x32_bf16(a0, b11, acc[1][0][1], 0, 0, 0);
      acc[1][1][1] = __builtin_amdgcn_mfma_f32_16x16x32_bf16(a1, b11, acc[1][1][1], 0, 0, 0);
      acc[1][2][1] = __builtin_amdgcn_mfma_f32_16x16x32_bf16(a2, b11, acc[1][2][1], 0, 0, 0);
      acc[1][3][1] = __builtin_amdgcn_mfma_f32_16x16x32_bf16(a3, b11, acc[1][3][1], 0, 0, 0);
    }

    // ---- epilogue per g: D layout col = h*16 + c, row = mt*16 + grp*4 + r ----
    #pragma unroll
    for (int gg = 0; gg < 2; ++gg) {
      int g = (gg == 0) ? g0 : g1;

      // row-max over 32 cols (valid rows: mt 0..2 all; mt3 only row 48 = grp0,reg0)
      float rm[3][4];
      #pragma unroll
      for (int mt = 0; mt < 3; ++mt)
        #pragma unroll
        for (int r = 0; r < 4; ++r)
          rm[mt][r] = max16(fmaxf(acc[gg][mt][0][r], acc[gg][mt][1][r]));
      float rm3 = max16(fmaxf(acc[gg][3][0][0], acc[gg][3][1][0]));

      float rsum = 0.f;
      #pragma unroll
      for (int mt = 0; mt < 3; ++mt)
        #pragma unroll
        for (int r = 0; r < 4; ++r)
          rsum += rm[mt][r];
      if (grp == 0) rsum += rm3;             // row 48
      rsum += __shfl_xor(rsum, 16);
      rsum += __shfl_xor(rsum, 32);

      // col-max over valid rows (in-lane), then across grp, then mean over cols
      float cm0 = acc[gg][0][0][0], cm1 = acc[gg][0][1][0];
      #pragma unroll
      for (int mt = 0; mt < 3; ++mt)
        #pragma unroll
        for (int r = 0; r < 4; ++r) {
          if (mt == 0 && r == 0) continue;
          cm0 = fmaxf(cm0, acc[gg][mt][0][r]);
          cm1 = fmaxf(cm1, acc[gg][mt][1][r]);
        }
      if (grp == 0) { cm0 = fmaxf(cm0, acc[gg][3][0][0]); cm1 = fmaxf(cm1, acc[gg][3][1][0]); }
      cm0 = fmaxf(cm0, __shfl_xor(cm0, 16));
      cm0 = fmaxf(cm0, __shfl_xor(cm0, 32));
      cm1 = fmaxf(cm1, __shfl_xor(cm1, 16));
      cm1 = fmaxf(cm1, __shfl_xor(cm1, 32));
      float csum = sum16(cm0 + cm1);

      if (lane == 0) {
        i2g[b * 256 + g] = rsum * (1.0f / NIMG);
        g2i[g * 256 + b] = csum * (1.0f / NGPS);
      }
    }
  }
}

// ---------------- kernel 3: per-row CE partials -------------------------------------
__global__ __launch_bounds__(256) void ce_kernel(
    const float* __restrict__ i2g, const float* __restrict__ g2i,
    const float* __restrict__ lsp, float* __restrict__ partial)
{
  int b = blockIdx.x, t = threadIdx.x, lane = t & 63, wv = t >> 6;
  float s = fminf(expf(lsp[0]), 100.0f);
  float v1 = s * i2g[b * 256 + t];
  float v2 = s * g2i[b * 256 + t];

  float m1 = v1, m2 = v2;
  #pragma unroll
  for (int d = 1; d < 64; d <<= 1) {
    m1 = fmaxf(m1, __shfl_xor(m1, d));
    m2 = fmaxf(m2, __shfl_xor(m2, d));
  }
  __shared__ float sm[2][4];
  if (lane == 0) { sm[0][wv] = m1; sm[1][wv] = m2; }
  __syncthreads();
  m1 = fmaxf(fmaxf(sm[0][0], sm[0][1]), fmaxf(sm[0][2], sm[0][3]));
  m2 = fmaxf(fmaxf(sm[1][0], sm[1][1]), fmaxf(sm[1][2], sm[1][3]));

  float e1 = expf(v1 - m1), e2 = expf(v2 - m2);
  #pragma unroll
  for (int d = 1; d < 64; d <<= 1) {
    e1 += __shfl_xor(e1, d);
    e2 += __shfl_xor(e2, d);
  }
  __shared__ float se[2][4];
  if (lane == 0) { se[0][wv] = e1; se[1][wv] = e2; }
  __syncthreads();
  if (t == 0) {
    float S1 = se[0][0] + se[0][1] + se[0][2] + se[0][3];
    float S2 = se[1][0] + se[1][1] + se[1][2] + se[1][3];
    float lse1 = m1 + logf(S1);
    float lse2 = m2 + logf(S2);
    partial[b] = (lse1 - s * i2g[b * 257]) + (lse2 - s * g2i[b * 257]);
  }
}

// ---------------- kernel 4: final scalar --------------------------------------------
__global__ __launch_bounds__(256) void finish_kernel(
    const float* __restrict__ partial, float* __restrict__ out)
{
  int t = threadIdx.x, lane = t & 63, wv = t >> 6;
  float v = partial[t];
  #pragma unroll
  for (int d = 1; d < 64; d <<= 1) v += __shfl_xor(v, d);
  __shared__ float sp[4];
  if (lane == 0) sp[wv] = v;
  __syncthreads();
  if (t == 0) out[0] = (sp[0] + sp[1] + sp[2] + sp[3]) * (1.0f / 512.0f);
}

extern "C" void kernel_launch(void* const* d_in, const int* in_sizes, int n_in,
                              void* d_out, int out_size, void* d_ws, size_t ws_size,
                              hipStream_t stream)
{
  const float* img = (const float*)d_in[0];
  const float* gps = (const float*)d_in[1];
  const float* lsp = (const float*)d_in[2];
  float* out = (float*)d_out;
  char* ws = (char*)d_ws;

  unsigned short* imgN = (unsigned short*)(ws);              //  8,388,608 B
  unsigned short* gpsN = (unsigned short*)(ws + 8388608);    //  4,194,304 B
  float* i2g     = (float*)(ws + 12582912);                  //    262,144 B
  float* g2i     = (float*)(ws + 12845056);                  //    262,144 B
  float* partial = (float*)(ws + 13107200);                  //      1,024 B

  norm_kernel<<<6144, 256, 0, stream>>>(img, gps, imgN, gpsN);
  pair_kernel<<<2048, 256, 0, stream>>>(imgN, gpsN, i2g, g2i);
  ce_kernel<<<256, 256, 0, stream>>>(i2g, g2i, lsp, partial);
  finish_kernel<<<1, 256, 0, stream>>>(partial, out);
}

// Round 4
// 151.927 us; speedup vs baseline: 1.6496x; 1.6496x over previous
//
#include <hip/hip_runtime.h>

#define BB   256
#define NIMG 49
#define NGPS 32
#define DIM  256
#define MPAD 64

typedef __attribute__((ext_vector_type(8))) __bf16 bf16x8;
typedef __attribute__((ext_vector_type(4))) float  f32x4;
typedef __attribute__((ext_vector_type(4))) unsigned short u16x4;

__device__ inline unsigned short f2bf(float f) {
  unsigned int u = __float_as_uint(f);
  u += 0x7fff + ((u >> 16) & 1);   // round-to-nearest-even
  return (unsigned short)(u >> 16);
}

// DPP cross-lane reduce helpers (VALU pipe, no DS traffic).
// 0xB1 quad_perm xor1, 0x4E quad_perm xor2, 0x141 row_half_mirror, 0x140 row_mirror
template<int CTRL>
__device__ inline float dppmax(float v) {
  float o = __int_as_float(__builtin_amdgcn_update_dpp(0, __float_as_int(v), CTRL, 0xF, 0xF, true));
  return fmaxf(v, o);
}
template<int CTRL>
__device__ inline float dppadd(float v) {
  float o = __int_as_float(__builtin_amdgcn_update_dpp(0, __float_as_int(v), CTRL, 0xF, 0xF, true));
  return v + o;
}
__device__ inline float max16(float v) {   // max across the 16 lanes of a DPP row
  v = dppmax<0xB1>(v); v = dppmax<0x4E>(v); v = dppmax<0x141>(v); v = dppmax<0x140>(v);
  return v;
}
__device__ inline float sum16(float v) {   // sum across the 16 lanes of a DPP row
  v = dppadd<0xB1>(v); v = dppadd<0x4E>(v); v = dppadd<0x141>(v); v = dppadd<0x140>(v);
  return v;
}

// ---------------- kernel 1: L2-normalize + cast to bf16 (img padded to 64 rows/b) ----
__global__ __launch_bounds__(256) void norm_kernel(
    const float* __restrict__ img, const float* __restrict__ gps,
    unsigned short* __restrict__ imgN, unsigned short* __restrict__ gpsN)
{
  int w    = (blockIdx.x * 256 + threadIdx.x) >> 6;  // one wave per row
  int lane = threadIdx.x & 63;
  const float* src;
  unsigned short* dst;
  if (w < BB * MPAD) {
    int b = w >> 6, n = w & 63;
    dst = imgN + (size_t)w * DIM;
    if (n >= NIMG) {                                  // zero padding rows
      u16x4 z = {0, 0, 0, 0};
      *reinterpret_cast<u16x4*>(dst + lane * 4) = z;
      return;
    }
    src = img + ((size_t)b * NIMG + n) * DIM;
  } else {
    int t = w - BB * MPAD;
    dst = gpsN + (size_t)t * DIM;
    src = gps + (size_t)t * DIM;
  }
  f32x4 x = *reinterpret_cast<const f32x4*>(src + lane * 4);
  float ss = x[0]*x[0] + x[1]*x[1] + x[2]*x[2] + x[3]*x[3];
  #pragma unroll
  for (int d = 1; d < 64; d <<= 1) ss += __shfl_xor(ss, d);
  float inv = 1.0f / fmaxf(sqrtf(ss), 1e-12f);
  u16x4 o;
  o[0] = f2bf(x[0]*inv); o[1] = f2bf(x[1]*inv);
  o[2] = f2bf(x[2]*inv); o[3] = f2bf(x[3]*inv);
  *reinterpret_cast<u16x4*>(dst + lane * 4) = o;
}

// ---------------- kernel 2: all-pairs 64x32 MFMA GEMM + fused max/mean reductions ----
// grid: 2048 blocks = 256 b * 8 g-chunks; 4 waves/block.
// A (img[b], 64x256 bf16 = 32KB) staged once in LDS, XOR-swizzled.
// Each wave owns 8 g's, processed 2 at a time (A fragment reuse x4 per ds_read).
// launch_bounds (256,2): combined VGPR+AGPR cap 256 -- (256,3)'s 168 cap caused
// a 148MB/dispatch scratch spill in round 3. Do NOT raise the min-waves arg.
__global__ __launch_bounds__(256, 2) void pair_kernel(
    const unsigned short* __restrict__ imgN, const unsigned short* __restrict__ gpsN,
    float* __restrict__ i2g, float* __restrict__ g2i)
{
  int tid  = threadIdx.x;
  int wv   = tid >> 6;
  int lane = tid & 63;
  int c    = lane & 15, grp = lane >> 4;
  int b    = blockIdx.x >> 3, gc = blockIdx.x & 7;

  __shared__ unsigned short As[MPAD * DIM];   // 32 KB

  // ---- stage A: lane = row, each wave writes 8 of 32 16B-slots per row ----
  {
    const unsigned short* src = imgN + ((size_t)(b * MPAD + lane)) * DIM;
    unsigned int rb = lane * 512;             // row byte base (512 B/row)
    unsigned int sw = (lane & 7) << 4;        // XOR swizzle for this row
    #pragma unroll
    for (int i = 0; i < 8; ++i) {
      int s = wv * 8 + i;                     // 16B slot index 0..31
      bf16x8 v = *reinterpret_cast<const bf16x8*>(src + s * 8);
      *reinterpret_cast<bf16x8*>(reinterpret_cast<char*>(As) + ((rb + s * 16) ^ sw)) = v;
    }
  }
  __syncthreads();

  const char* Ab = reinterpret_cast<const char*>(As);
  unsigned int swr = (c & 7) << 4;            // read-side swizzle (r&7 == c&7)
  unsigned int rbase0 = (c) * 512;            // mt stride added as mt*16*512

  #pragma unroll 1
  for (int st = 0; st < 4; ++st) {
    int g0 = gc * 32 + wv * 8 + st * 2;
    int g1 = g0 + 1;
    const unsigned short* p0 = gpsN + ((size_t)g0 * NGPS + c) * DIM + grp * 8;
    const unsigned short* p1 = gpsN + ((size_t)g1 * NGPS + c) * DIM + grp * 8;

    f32x4 acc[2][4][2];
    #pragma unroll
    for (int gg = 0; gg < 2; ++gg)
      #pragma unroll
      for (int mt = 0; mt < 4; ++mt) {
        acc[gg][mt][0] = (f32x4){0.f, 0.f, 0.f, 0.f};
        acc[gg][mt][1] = (f32x4){0.f, 0.f, 0.f, 0.f};
      }

    // 1-deep software pipeline on the 4 global B loads per k-chunk.
    bf16x8 nb00 = *reinterpret_cast<const bf16x8*>(p0);
    bf16x8 nb01 = *reinterpret_cast<const bf16x8*>(p0 + 16 * DIM);
    bf16x8 nb10 = *reinterpret_cast<const bf16x8*>(p1);
    bf16x8 nb11 = *reinterpret_cast<const bf16x8*>(p1 + 16 * DIM);

    #pragma unroll
    for (int kc = 0; kc < 8; ++kc) {
      bf16x8 b00 = nb00, b01 = nb01, b10 = nb10, b11 = nb11;
      if (kc < 7) {
        nb00 = *reinterpret_cast<const bf16x8*>(p0 + (kc + 1) * 32);
        nb01 = *reinterpret_cast<const bf16x8*>(p0 + 16 * DIM + (kc + 1) * 32);
        nb10 = *reinterpret_cast<const bf16x8*>(p1 + (kc + 1) * 32);
        nb11 = *reinterpret_cast<const bf16x8*>(p1 + 16 * DIM + (kc + 1) * 32);
      }
      unsigned int off = ((unsigned)(grp * 16 + kc * 64)) ^ swr;
      bf16x8 a0 = *reinterpret_cast<const bf16x8*>(Ab + rbase0 +  0 * 8192 + off);
      bf16x8 a1 = *reinterpret_cast<const bf16x8*>(Ab + rbase0 +  1 * 8192 + off);
      bf16x8 a2 = *reinterpret_cast<const bf16x8*>(Ab + rbase0 +  2 * 8192 + off);
      bf16x8 a3 = *reinterpret_cast<const bf16x8*>(Ab + rbase0 +  3 * 8192 + off);
      acc[0][0][0] = __builtin_amdgcn_mfma_f32_16x16x32_bf16(a0, b00, acc[0][0][0], 0, 0, 0);
      acc[0][1][0] = __builtin_amdgcn_mfma_f32_16x16x32_bf16(a1, b00, acc[0][1][0], 0, 0, 0);
      acc[0][2][0] = __builtin_amdgcn_mfma_f32_16x16x32_bf16(a2, b00, acc[0][2][0], 0, 0, 0);
      acc[0][3][0] = __builtin_amdgcn_mfma_f32_16x16x32_bf16(a3, b00, acc[0][3][0], 0, 0, 0);
      acc[0][0][1] = __builtin_amdgcn_mfma_f32_16x16x32_bf16(a0, b01, acc[0][0][1], 0, 0, 0);
      acc[0][1][1] = __builtin_amdgcn_mfma_f32_16x16x32_bf16(a1, b01, acc[0][1][1], 0, 0, 0);
      acc[0][2][1] = __builtin_amdgcn_mfma_f32_16x16x32_bf16(a2, b01, acc[0][2][1], 0, 0, 0);
      acc[0][3][1] = __builtin_amdgcn_mfma_f32_16x16x32_bf16(a3, b01, acc[0][3][1], 0, 0, 0);
      acc[1][0][0] = __builtin_amdgcn_mfma_f32_16x16x32_bf16(a0, b10, acc[1][0][0], 0, 0, 0);
      acc[1][1][0] = __builtin_amdgcn_mfma_f32_16x16x32_bf16(a1, b10, acc[1][1][0], 0, 0, 0);
      acc[1][2][0] = __builtin_amdgcn_mfma_f32_16x16x32_bf16(a2, b10, acc[1][2][0], 0, 0, 0);
      acc[1][3][0] = __builtin_amdgcn_mfma_f32_16x16x32_bf16(a3, b10, acc[1][3][0], 0, 0, 0);
      acc[1][0][1] = __builtin_amdgcn_mfma_f32_16x16x32_bf16(a0, b11, acc[1][0][1], 0, 0, 0);
      acc[1][1][1] = __builtin_amdgcn_mfma_f32_16x16x32_bf16(a1, b11, acc[1][1][1], 0, 0, 0);
      acc[1][2][1] = __builtin_amdgcn_mfma_f32_16x16x32_bf16(a2, b11, acc[1][2][1], 0, 0, 0);
      acc[1][3][1] = __builtin_amdgcn_mfma_f32_16x16x32_bf16(a3, b11, acc[1][3][1], 0, 0, 0);
    }

    // ---- epilogue per g: D layout col = h*16 + c, row = mt*16 + grp*4 + r ----
    #pragma unroll
    for (int gg = 0; gg < 2; ++gg) {
      int g = (gg == 0) ? g0 : g1;

      // row-max over 32 cols (valid rows: mt 0..2 all; mt3 only row 48 = grp0,reg0)
      float rm[3][4];
      #pragma unroll
      for (int mt = 0; mt < 3; ++mt)
        #pragma unroll
        for (int r = 0; r < 4; ++r)
          rm[mt][r] = max16(fmaxf(acc[gg][mt][0][r], acc[gg][mt][1][r]));
      float rm3 = max16(fmaxf(acc[gg][3][0][0], acc[gg][3][1][0]));

      float rsum = 0.f;
      #pragma unroll
      for (int mt = 0; mt < 3; ++mt)
        #pragma unroll
        for (int r = 0; r < 4; ++r)
          rsum += rm[mt][r];
      if (grp == 0) rsum += rm3;             // row 48
      rsum += __shfl_xor(rsum, 16);
      rsum += __shfl_xor(rsum, 32);

      // col-max over valid rows (in-lane), then across grp, then mean over cols
      float cm0 = acc[gg][0][0][0], cm1 = acc[gg][0][1][0];
      #pragma unroll
      for (int mt = 0; mt < 3; ++mt)
        #pragma unroll
        for (int r = 0; r < 4; ++r) {
          if (mt == 0 && r == 0) continue;
          cm0 = fmaxf(cm0, acc[gg][mt][0][r]);
          cm1 = fmaxf(cm1, acc[gg][mt][1][r]);
        }
      if (grp == 0) { cm0 = fmaxf(cm0, acc[gg][3][0][0]); cm1 = fmaxf(cm1, acc[gg][3][1][0]); }
      cm0 = fmaxf(cm0, __shfl_xor(cm0, 16));
      cm0 = fmaxf(cm0, __shfl_xor(cm0, 32));
      cm1 = fmaxf(cm1, __shfl_xor(cm1, 16));
      cm1 = fmaxf(cm1, __shfl_xor(cm1, 32));
      float csum = sum16(cm0 + cm1);

      if (lane == 0) {
        i2g[b * 256 + g] = rsum * (1.0f / NIMG);
        g2i[g * 256 + b] = csum * (1.0f / NGPS);
      }
    }
  }
}

// ---------------- kernel 3: per-row CE partials -------------------------------------
__global__ __launch_bounds__(256) void ce_kernel(
    const float* __restrict__ i2g, const float* __restrict__ g2i,
    const float* __restrict__ lsp, float* __restrict__ partial)
{
  int b = blockIdx.x, t = threadIdx.x, lane = t & 63, wv = t >> 6;
  float s = fminf(expf(lsp[0]), 100.0f);
  float v1 = s * i2g[b * 256 + t];
  float v2 = s * g2i[b * 256 + t];

  float m1 = v1, m2 = v2;
  #pragma unroll
  for (int d = 1; d < 64; d <<= 1) {
    m1 = fmaxf(m1, __shfl_xor(m1, d));
    m2 = fmaxf(m2, __shfl_xor(m2, d));
  }
  __shared__ float sm[2][4];
  if (lane == 0) { sm[0][wv] = m1; sm[1][wv] = m2; }
  __syncthreads();
  m1 = fmaxf(fmaxf(sm[0][0], sm[0][1]), fmaxf(sm[0][2], sm[0][3]));
  m2 = fmaxf(fmaxf(sm[1][0], sm[1][1]), fmaxf(sm[1][2], sm[1][3]));

  float e1 = expf(v1 - m1), e2 = expf(v2 - m2);
  #pragma unroll
  for (int d = 1; d < 64; d <<= 1) {
    e1 += __shfl_xor(e1, d);
    e2 += __shfl_xor(e2, d);
  }
  __shared__ float se[2][4];
  if (lane == 0) { se[0][wv] = e1; se[1][wv] = e2; }
  __syncthreads();
  if (t == 0) {
    float S1 = se[0][0] + se[0][1] + se[0][2] + se[0][3];
    float S2 = se[1][0] + se[1][1] + se[1][2] + se[1][3];
    float lse1 = m1 + logf(S1);
    float lse2 = m2 + logf(S2);
    partial[b] = (lse1 - s * i2g[b * 257]) + (lse2 - s * g2i[b * 257]);
  }
}

// ---------------- kernel 4: final scalar --------------------------------------------
__global__ __launch_bounds__(256) void finish_kernel(
    const float* __restrict__ partial, float* __restrict__ out)
{
  int t = threadIdx.x, lane = t & 63, wv = t >> 6;
  float v = partial[t];
  #pragma unroll
  for (int d = 1; d < 64; d <<= 1) v += __shfl_xor(v, d);
  __shared__ float sp[4];
  if (lane == 0) sp[wv] = v;
  __syncthreads();
  if (t == 0) out[0] = (sp[0] + sp[1] + sp[2] + sp[3]) * (1.0f / 512.0f);
}

extern "C" void kernel_launch(void* const* d_in, const int* in_sizes, int n_in,
                              void* d_out, int out_size, void* d_ws, size_t ws_size,
                              hipStream_t stream)
{
  const float* img = (const float*)d_in[0];
  const float* gps = (const float*)d_in[1];
  const float* lsp = (const float*)d_in[2];
  float* out = (float*)d_out;
  char* ws = (char*)d_ws;

  unsigned short* imgN = (unsigned short*)(ws);              //  8,388,608 B
  unsigned short* gpsN = (unsigned short*)(ws + 8388608);    //  4,194,304 B
  float* i2g     = (float*)(ws + 12582912);                  //    262,144 B
  float* g2i     = (float*)(ws + 12845056);                  //    262,144 B
  float* partial = (float*)(ws + 13107200);                  //      1,024 B

  norm_kernel<<<6144, 256, 0, stream>>>(img, gps, imgN, gpsN);
  pair_kernel<<<2048, 256, 0, stream>>>(imgN, gpsN, i2g, g2i);
  ce_kernel<<<256, 256, 0, stream>>>(i2g, g2i, lsp, partial);
  finish_kernel<<<1, 256, 0, stream>>>(partial, out);
}